// Round 10
// baseline (196.951 us; speedup 1.0000x reference)
//
#include <hip/hip_runtime.h>

#define NFEAT 64

// v32 = proven v31 skeleton + u8-packed sort (fewer passes) + fused scans.
// R9 post-mortem: place/scan fixes bought 5.4us of a predicted 22-37 ->
// non-gather cost is mostly NOT in computable kernel work; suspected fixed
// per-iteration floor. This round removes the last computable slack:
//  - u8 LDS hist/rank (4 ids/word, 50KB covers 50048 ids): dst hist 1 pass,
//    src hist 2, place 1 with pre folded into the u8 counter
//    (pre+rank <= max in-degree ~60 << 255; chunk counts <= ~6 << 255).
//  - scan1 folded into norm (256-elem chunks, LDS reduce -> bsum);
//    scan23 at 196x256, one element/thread, uniform barriers.
// 6 dispatches: hist_src | hist_dst | norm | scan23 | place | gather.
#define PR8 50048               // ids per y-pass (u8-packed)
#define PW8 (PR8 / 4)           // 12512 ints = 50048 B LDS
#define NB_IN  256              // dst-side edge chunks (grid = 256 blocks)
#define NB_OUT 128              // src-side edge chunks (grid = 128 x 2)

// ---------------------------------------------------------------------------
// u8-packed LDS histogram: block (b,y) counts chunk b of idx[] over range
// [y*PR8, ...). 4 ids/word; field totals ~<=6 << 255, no cross-byte carry.
// Flush as u32 stores (row offsets 4-aligned: n % 4 == 0, rbase % 4 == 0).
// ---------------------------------------------------------------------------
__global__ __launch_bounds__(1024) void v32_hist(
        const int* __restrict__ idx, unsigned char* __restrict__ cnt,
        int E, int n, int Ec) {
    __shared__ unsigned int lh[PW8];
    int b = blockIdx.x, t = threadIdx.x, T = blockDim.x;
    int rbase = blockIdx.y * PR8;
    int rend = rbase + PR8; if (rend > n) rend = n;
    int W = rend - rbase;
    if (W <= 0) return;
    int Wp = (W + 3) >> 2;
    for (int i = t; i < Wp; i += T) lh[i] = 0;
    __syncthreads();
    int lo = b * Ec;
    int hi = lo + Ec; if (hi > E) hi = E;
    if (lo < hi) {
        int nq = (hi - lo) >> 2;            // lo is 16B-aligned (Ec % 4 == 0)
#define V32_H(val)                                                            \
        {                                                                     \
            unsigned r = (unsigned)((val) - rbase);                           \
            if (r < (unsigned)W)                                              \
                atomicAdd(&lh[r >> 2], 1u << ((r & 3) << 3));                 \
        }
        for (int q = t; q < nq; q += T) {
            int i = lo + (q << 2);
            int4 e = *(const int4*)(idx + i);
            V32_H(e.x) V32_H(e.y) V32_H(e.z) V32_H(e.w)
        }
        for (int i = lo + (nq << 2) + t; i < hi; i += T) V32_H(idx[i]);
#undef V32_H
    }
    __syncthreads();
    unsigned char* row = cnt + (size_t)b * n + rbase;
    if (((((uintptr_t)row) & 3) == 0) && ((W & 3) == 0)) {
        unsigned int* row32 = (unsigned int*)row;
        for (int i = t; i < Wp; i += T) row32[i] = lh[i];
    } else {
        for (int i = t; i < W; i += T)
            row[i] = (unsigned char)((lh[i >> 2] >> ((i & 3) << 3)) & 0xff);
    }
}

// ---------------------------------------------------------------------------
// Norm (+ fused bsum): one thread per id. nsrc col-sums (u8, coalesced per
// j); cnt_in column-wise exclusive prefix IN PLACE (u8; pre <= deg <= ~60);
// deg_in + ndst; per-block (256-elem chunk) LDS reduce -> bsum[b].
// ---------------------------------------------------------------------------
__global__ __launch_bounds__(256) void v32_norm(
        const unsigned char* __restrict__ cnt_out,
        unsigned char* __restrict__ cnt_in,
        int* __restrict__ deg_in,
        float* __restrict__ nsrc, float* __restrict__ ndst,
        int* __restrict__ bsum, int n_src, int n_dst) {
    __shared__ int red[256];
    int b = blockIdx.x, t = threadIdx.x;
    int i = b * 256 + t;
    if (i < n_src) {
        const unsigned char* p = cnt_out + i;
        int s = 0;
#pragma unroll 8
        for (int j = 0; j < NB_OUT; ++j) { s += *p; p += n_src; }
        nsrc[i] = rsqrtf(fmaxf((float)s, 1.0f));
    }
    int dval = 0;
    if (i < n_dst) {
        unsigned char* p = cnt_in + i;
        int a = 0;
#pragma unroll 8
        for (int j = 0; j < NB_IN; ++j) {
            int c = *p;
            *p = (unsigned char)a;
            a += c;
            p += n_dst;
        }
        deg_in[i] = a;
        ndst[i] = rsqrtf(fmaxf((float)a, 1.0f));
        dval = a;
    }
    // bsum only for blocks covering the dst range
    int nch = (n_dst + 255) >> 8;
    if (b < nch) {
        red[t] = dval;
        __syncthreads();
        for (int o = 128; o > 0; o >>= 1) {
            if (t < o) red[t] += red[t + o];
            __syncthreads();
        }
        if (t == 0) bsum[b] = red[0];
    }
}

// ---------------------------------------------------------------------------
// scan23: grid = nch (196) x 256, one dst element per thread. Every block
// HS-scans bsum[nch] in LDS (parallel, uniform barriers), then HS-scans its
// own 256 deg values -> row_start. No serial chains.
// ---------------------------------------------------------------------------
__global__ __launch_bounds__(256) void v32_scan23(
        const int* __restrict__ deg_in, const int* __restrict__ bsum,
        int* __restrict__ row_start, int n_dst) {
    __shared__ int bs[256];
    __shared__ int tsum[256];
    int b = blockIdx.x, t = threadIdx.x;
    int nch = (n_dst + 255) >> 8;
    bs[t] = (t < nch) ? bsum[t] : 0;
    __syncthreads();
    for (int off = 1; off < 256; off <<= 1) {
        int v = (t >= off) ? bs[t - off] : 0;
        __syncthreads();
        bs[t] += v;
        __syncthreads();
    }
    int i = b * 256 + t;
    int dval = (i < n_dst) ? deg_in[i] : 0;
    tsum[t] = dval;
    __syncthreads();
    for (int off = 1; off < 256; off <<= 1) {
        int v = (t >= off) ? tsum[t - off] : 0;
        __syncthreads();
        tsum[t] += v;
        __syncthreads();
    }
    int boffs = b ? bs[b - 1] : 0;
    if (i < n_dst) row_start[i] = boffs + tsum[t] - dval;
    if (b == 0 && t == 0) row_start[n_dst] = bs[nch - 1];
}

// ---------------------------------------------------------------------------
// Place (u8, pre folded): LDS counter initialized FROM the block's prow
// slice (u8 layout == counter layout, coalesced u32 copy). atomicAdd
// returns pre+rank combined: slot = row_start[d] + old8. Single y-pass
// (PR8 >= n_dst). pre+rank <= deg (~<=60) << 255: no cross-byte carry.
// ---------------------------------------------------------------------------
__global__ __launch_bounds__(1024) void v32_place(
        const int* __restrict__ esrc, const int* __restrict__ edst,
        const unsigned char* __restrict__ pre, const int* __restrict__ row_start,
        int* __restrict__ sorted_src, int E, int n_dst, int Ec) {
    __shared__ unsigned int lh[PW8];
    int b = blockIdx.x, t = threadIdx.x, T = blockDim.x;
    int rbase = blockIdx.y * PR8;
    int rend = rbase + PR8; if (rend > n_dst) rend = n_dst;
    int W = rend - rbase;
    if (W <= 0) return;
    const unsigned char* prow = pre + (size_t)b * n_dst + rbase;
    int full = W >> 2;
    if ((((uintptr_t)prow) & 3) == 0) {
        const unsigned int* prow32 = (const unsigned int*)prow;
        for (int i = t; i < full; i += T) lh[i] = prow32[i];
        if (t == 0) {
            for (int r = full << 2; r < W; ++r) {
                int sh = (r & 3) << 3;
                unsigned w = lh[r >> 2] & ~(0xffu << sh);
                lh[r >> 2] = w | ((unsigned)prow[r] << sh);
            }
        }
    } else {
        for (int i = t; i < ((W + 3) >> 2); i += T) lh[i] = 0;
        __syncthreads();
        for (int r = t; r < W; r += T)
            atomicOr(&lh[r >> 2], (unsigned)prow[r] << ((r & 3) << 3));
    }
    __syncthreads();
    int lo = b * Ec;
    int hi = lo + Ec; if (hi > E) hi = E;
    if (lo >= hi) return;
    int nq = (hi - lo) >> 2;
#define V32_PL(dd, ss)                                                        \
    {                                                                         \
        unsigned r = (unsigned)((dd) - rbase);                                \
        if (r < (unsigned)W) {                                                \
            int sh = (r & 3) << 3;                                            \
            unsigned old = atomicAdd(&lh[r >> 2], 1u << sh);                  \
            int pr = (int)((old >> sh) & 0xff);                               \
            int slot = row_start[dd] + pr;                                    \
            if ((unsigned)slot < (unsigned)E) sorted_src[slot] = (ss);        \
        }                                                                     \
    }
    for (int q = t; q < nq; q += T) {
        int i = lo + (q << 2);
        int4 dv = *(const int4*)(edst + i);
        int4 sv = *(const int4*)(esrc + i);
        V32_PL(dv.x, sv.x)
        V32_PL(dv.y, sv.y)
        V32_PL(dv.z, sv.z)
        V32_PL(dv.w, sv.w)
    }
    for (int i = lo + (nq << 2) + t; i < hi; i += T) {
        int d = edst[i];
        int s = esrc[i];
        V32_PL(d, s)
    }
#undef V32_PL
}

// ---------------------------------------------------------------------------
// Gather (proven v26 shape, unchanged): wave = 1 dst row; 64 lanes =
// 4 edge-groups x 16 feature-lanes x float4; 4-deep unroll.
// ---------------------------------------------------------------------------
__global__ void v26_gather(const float* __restrict__ feat,
                           const int* __restrict__ sorted_src,
                           const int* __restrict__ row_start,
                           const float* __restrict__ nsrc,
                           const float* __restrict__ ndst,
                           float* __restrict__ out,
                           int n_src, int n_dst) {
    int gid = blockIdx.x * blockDim.x + threadIdx.x;
    int d = gid >> 6;
    if (d >= n_dst) return;
    int lane = threadIdx.x & 63;
    int g = lane >> 4;          // edge slot within a 4-edge step
    int lg = lane & 15;         // feature chunk (float4)
    int lo = row_start[d], hi = row_start[d + 1];
    int nmax = n_src - 1;
    float4 a0 = {0,0,0,0}, a1 = {0,0,0,0}, a2 = {0,0,0,0}, a3 = {0,0,0,0};
#define V26_G(kk, acc)                                                        \
    {                                                                         \
        int s_ = sorted_src[(kk) + g];                                        \
        s_ = min(max(s_, 0), nmax);                                           \
        float w_ = nsrc[s_];                                                  \
        float4 v_ = *(const float4*)(feat + (size_t)s_ * NFEAT + (lg << 2));  \
        acc.x += v_.x * w_; acc.y += v_.y * w_;                               \
        acc.z += v_.z * w_; acc.w += v_.w * w_;                               \
    }
    int k = lo;
    for (; k + 15 < hi; k += 16) {
        V26_G(k, a0)
        V26_G(k + 4, a1)
        V26_G(k + 8, a2)
        V26_G(k + 12, a3)
    }
    for (; k + 3 < hi; k += 4) {
        V26_G(k, a0)
    }
    if (k + g < hi) {
        V26_G(k, a1)
    }
#undef V26_G
    float4 a;
    a.x = (a0.x + a1.x) + (a2.x + a3.x);
    a.y = (a0.y + a1.y) + (a2.y + a3.y);
    a.z = (a0.z + a1.z) + (a2.z + a3.z);
    a.w = (a0.w + a1.w) + (a2.w + a3.w);
    a.x += __shfl_xor(a.x, 16); a.x += __shfl_xor(a.x, 32);
    a.y += __shfl_xor(a.y, 16); a.y += __shfl_xor(a.y, 32);
    a.z += __shfl_xor(a.z, 16); a.z += __shfl_xor(a.z, 32);
    a.w += __shfl_xor(a.w, 16); a.w += __shfl_xor(a.w, 32);
    if (g == 0) {
        float sc = ndst[d];
        float4 r;
        r.x = a.x * sc; r.y = a.y * sc; r.z = a.z * sc; r.w = a.w * sc;
        *(float4*)(out + (size_t)d * NFEAT + (lg << 2)) = r;
    }
}

// ---------------------------------------------------------------------------
// v23 fallback (proven path) — only if sizes break v32's assumptions
// ---------------------------------------------------------------------------
#define SCAN_BLOCKS 128

__global__ void v23_zero(int* __restrict__ deg_out, int* __restrict__ deg_in,
                         int n_src, int n_dst) {
    int i = blockIdx.x * blockDim.x + threadIdx.x;
    if (i < n_src) deg_out[i] = 0;
    if (i < n_dst) deg_in[i] = 0;
}
__global__ void v23_deg(const int* __restrict__ esrc, const int* __restrict__ edst,
                        int* __restrict__ deg_out, int* __restrict__ deg_in,
                        int E, int n_src, int n_dst) {
    int i = blockIdx.x * blockDim.x + threadIdx.x;
    if (i >= E) return;
    int s = esrc[i];
    int d = edst[i];
    if ((unsigned)s < (unsigned)n_src) atomicAdd(&deg_out[s], 1);
    if ((unsigned)d < (unsigned)n_dst) atomicAdd(&deg_in[d], 1);
}
__global__ void v23_norm(const int* __restrict__ deg_out, const int* __restrict__ deg_in,
                         float* __restrict__ nsrc, float* __restrict__ ndst,
                         int n_src, int n_dst) {
    int i = blockIdx.x * blockDim.x + threadIdx.x;
    if (i < n_src) nsrc[i] = rsqrtf(fmaxf((float)deg_out[i], 1.0f));
    if (i < n_dst) ndst[i] = rsqrtf(fmaxf((float)deg_in[i], 1.0f));
}
__global__ void v23_scan1(const int* __restrict__ deg_in, int* __restrict__ bsum,
                          int n_dst, int chunk) {
    __shared__ int red[256];
    int b = blockIdx.x, t = threadIdx.x;
    int lo = b * chunk;
    int hi = lo + chunk; if (hi > n_dst) hi = n_dst;
    int s = 0;
    for (int i = lo + t; i < hi; i += 256) s += deg_in[i];
    red[t] = s;
    __syncthreads();
    for (int o = 128; o > 0; o >>= 1) {
        if (t < o) red[t] += red[t + o];
        __syncthreads();
    }
    if (t == 0) bsum[b] = red[0];
}
__global__ void v23_scan2(int* __restrict__ bsum, int* __restrict__ boff,
                          int* __restrict__ row_start, int n_dst) {
    if (threadIdx.x == 0) {
        int a = 0;
        for (int k = 0; k < SCAN_BLOCKS; ++k) { boff[k] = a; a += bsum[k]; }
        row_start[n_dst] = a;
    }
}
__global__ void v23_scan3(const int* __restrict__ deg_in, const int* __restrict__ boff,
                          int* __restrict__ row_start, int* __restrict__ cursor,
                          int n_dst, int chunk) {
    __shared__ int tsum[256];
    int b = blockIdx.x, t = threadIdx.x;
    int lo = b * chunk;
    int hi = lo + chunk; if (hi > n_dst) hi = n_dst;
    int per = (chunk + 255) / 256;
    int mylo = lo + t * per;
    int myhi = mylo + per; if (myhi > hi) myhi = hi;
    int s = 0;
    for (int i = mylo; i < myhi; ++i) s += deg_in[i];
    tsum[t] = s;
    __syncthreads();
    if (t == 0) {
        int a = 0;
        for (int k = 0; k < 256; ++k) { int v = tsum[k]; tsum[k] = a; a += v; }
    }
    __syncthreads();
    int a = boff[b] + tsum[t];
    for (int i = mylo; i < myhi; ++i) {
        row_start[i] = a;
        cursor[i] = a;
        a += deg_in[i];
    }
}
__global__ void v23_place(const int* __restrict__ esrc, const int* __restrict__ edst,
                          int* __restrict__ cursor, int* __restrict__ sorted_src,
                          int E, int n_src, int n_dst) {
    int i = blockIdx.x * blockDim.x + threadIdx.x;
    if (i >= E) return;
    int s = esrc[i];
    int d = edst[i];
    if ((unsigned)s >= (unsigned)n_src) return;
    if ((unsigned)d >= (unsigned)n_dst) return;
    int slot = atomicAdd(&cursor[d], 1);
    sorted_src[slot] = s;
}

// ---------------------------------------------------------------------------

extern "C" void kernel_launch(void* const* d_in, const int* in_sizes, int n_in,
                              void* d_out, int out_size, void* d_ws, size_t ws_size,
                              hipStream_t stream) {
    const float* feat = (const float*)d_in[0];
    const int* esrc = (const int*)d_in[1];
    const int* edst = (const int*)d_in[2];
    float* out = (float*)d_out;

    const int n_src = in_sizes[0] / NFEAT;   // 100000
    const int E     = in_sizes[1];           // 1250000
    const int n_dst = out_size / NFEAT;      // 50000

    const int B = 256;
    int nmax = n_src > n_dst ? n_src : n_dst;
    int chunk = (n_dst + SCAN_BLOCKS - 1) / SCAN_BLOCKS;

    size_t sz_cnt_in  = ((size_t)NB_IN  * (size_t)n_dst + 255) & ~(size_t)255;
    size_t sz_cnt_out = ((size_t)NB_OUT * (size_t)n_src + 255) & ~(size_t)255;
    size_t sz_fixed = (size_t)E * 4                 // sorted_src
                    + (size_t)n_dst * 4             // deg_in
                    + (size_t)n_src * 4             // nsrc
                    + (size_t)n_dst * 4             // ndst
                    + (size_t)n_dst * 4             // cursor (fallback only)
                    + (size_t)(n_dst + 1) * 4       // row_start
                    + 256 * 4 + SCAN_BLOCKS * 4 + 512;
    int nch = (n_dst + 255) >> 8;
    bool big = (ws_size >= sz_cnt_in + sz_cnt_out + sz_fixed)
             && (nch <= 256) && ((n_dst & 3) == 0) && ((n_src & 3) == 0);

    if (big) {
        char* ws = (char*)d_ws;
        size_t off = 0;
        unsigned char* cnt_in  = (unsigned char*)(ws + off); off += sz_cnt_in;
        unsigned char* cnt_out = (unsigned char*)(ws + off); off += sz_cnt_out;
        int*   sorted_src = (int*)(ws + off);   off += (size_t)E * 4;
        int*   deg_in     = (int*)(ws + off);   off += (size_t)n_dst * 4;
        float* nsrc       = (float*)(ws + off); off += (size_t)n_src * 4;
        float* ndst       = (float*)(ws + off); off += (size_t)n_dst * 4;
        int*   cursor     = (int*)(ws + off);   off += (size_t)n_dst * 4;
        int*   row_start  = (int*)(ws + off);   off += (size_t)(n_dst + 1) * 4;
        int*   bsum       = (int*)(ws + off);   off += 256 * 4;
        (void)cursor;

        int Ec_in  = (((E + NB_IN  - 1) / NB_IN ) + 3) & ~3;   // 4884
        int Ec_out = (((E + NB_OUT - 1) / NB_OUT) + 3) & ~3;   // 9768
        int P_in  = (n_dst + PR8 - 1) / PR8;                   // 1
        int P_out = (n_src + PR8 - 1) / PR8;                   // 2

        dim3 gout(NB_OUT, P_out), gin(NB_IN, P_in);

        v32_hist<<<gout, 1024, 0, stream>>>(esrc, cnt_out, E, n_src, Ec_out);
        v32_hist<<<gin,  1024, 0, stream>>>(edst, cnt_in,  E, n_dst, Ec_in);
        v32_norm<<<(nmax + B - 1) / B, B, 0, stream>>>(cnt_out, cnt_in, deg_in,
                                                       nsrc, ndst, bsum,
                                                       n_src, n_dst);
        v32_scan23<<<nch, B, 0, stream>>>(deg_in, bsum, row_start, n_dst);
        v32_place<<<gin, 1024, 0, stream>>>(esrc, edst, cnt_in, row_start,
                                            sorted_src, E, n_dst, Ec_in);
        long long gthreads = (long long)n_dst * 64;
        v26_gather<<<(int)((gthreads + B - 1) / B), B, 0, stream>>>(feat, sorted_src,
                                                                    row_start, nsrc, ndst,
                                                                    out, n_src, n_dst);
    } else {
        // v23 fallback layout
        char* ws = (char*)d_ws;
        size_t off = 0;
        int*   deg_out    = (int*)(ws + off);   off += (size_t)n_src * 4;
        int*   deg_in     = (int*)(ws + off);   off += (size_t)n_dst * 4;
        float* nsrc       = (float*)(ws + off); off += (size_t)n_src * 4;
        float* ndst       = (float*)(ws + off); off += (size_t)n_dst * 4;
        int*   row_start  = (int*)(ws + off);   off += (size_t)(n_dst + 1) * 4;
        int*   cursor     = (int*)(ws + off);   off += (size_t)n_dst * 4;
        int*   bsum       = (int*)(ws + off);   off += SCAN_BLOCKS * 4;
        int*   boff       = (int*)(ws + off);   off += SCAN_BLOCKS * 4;
        int*   sorted_src = (int*)(ws + off);   off += (size_t)E * 4;

        v23_zero<<<(nmax + B - 1) / B, B, 0, stream>>>(deg_out, deg_in, n_src, n_dst);
        v23_deg<<<(E + B - 1) / B, B, 0, stream>>>(esrc, edst, deg_out, deg_in,
                                                   E, n_src, n_dst);
        v23_norm<<<(nmax + B - 1) / B, B, 0, stream>>>(deg_out, deg_in, nsrc, ndst,
                                                       n_src, n_dst);
        v23_scan1<<<SCAN_BLOCKS, B, 0, stream>>>(deg_in, bsum, n_dst, chunk);
        v23_scan2<<<1, 64, 0, stream>>>(bsum, boff, row_start, n_dst);
        v23_scan3<<<SCAN_BLOCKS, B, 0, stream>>>(deg_in, boff, row_start, cursor,
                                                 n_dst, chunk);
        v23_place<<<(E + B - 1) / B, B, 0, stream>>>(esrc, edst, cursor, sorted_src,
                                                     E, n_src, n_dst);
        long long gthreads = (long long)n_dst * 64;
        v26_gather<<<(int)((gthreads + B - 1) / B), B, 0, stream>>>(feat, sorted_src,
                                                                    row_start, nsrc, ndst,
                                                                    out, n_src, n_dst);
    }
}

// Round 11
// 181.055 us; speedup vs baseline: 1.0878x; 1.0878x over previous
//
#include <hip/hip_runtime.h>

#define NFEAT 64
#define SCAN_BLOCKS 128

// v31 (byte-identical revert; best verified artifact: 182.4us in R9).
// R10 post-mortem: v32's u8 single-pass rework regressed to 197 despite
// lower computable traffic -> confirms the non-gather ~130us is a
// latency/ramp floor, not traffic-bound; gather (47us) is L2-miss-traffic
// bound (FETCH 143.5MB @ ~3.4TB/s) with fully-coalesced reads of a
// randomly-permuted src stream. This is the practical ceiling candidate.
#define PRANGE 25600            // ids per y-pass
#define PWORDS (PRANGE / 2)     // 12800 ints = 51.2 KiB LDS
#define NB_IN  128              // dst-side edge chunks (max rank 9766 < 64K)
#define NB_OUT 64               // src-side edge chunks (max rank 19532 < 64K)

// ---------------------------------------------------------------------------
// Packed LDS histogram: block (b,y) counts chunk b of idx[] over id range
// [y*PRANGE, ...). 2 ids/word; field totals <= chunk size << 65536 so no
// cross-field carry. Flush as uint stores (rbase and n are even).
// ---------------------------------------------------------------------------
__global__ __launch_bounds__(1024) void v27_hist(
        const int* __restrict__ idx, unsigned short* __restrict__ cnt,
        int E, int n, int Ec) {
    __shared__ int lh[PWORDS];
    int b = blockIdx.x, t = threadIdx.x, T = blockDim.x;
    int rbase = blockIdx.y * PRANGE;
    int rend = rbase + PRANGE; if (rend > n) rend = n;
    int W = rend - rbase;
    if (W <= 0) return;
    int Wp = (W + 1) >> 1;
    for (int i = t; i < Wp; i += T) lh[i] = 0;
    __syncthreads();
    int lo = b * Ec;
    int hi = lo + Ec; if (hi > E) hi = E;
    if (lo < hi) {
        int cntE = hi - lo;
        int nq = cntE >> 2;                 // lo is 16B-aligned (Ec % 4 == 0)
#define V27_H(val)                                                            \
        {                                                                     \
            unsigned r = (unsigned)((val) - rbase);                           \
            if (r < (unsigned)W)                                              \
                atomicAdd(&lh[r >> 1], 1 << ((r & 1) << 4));                  \
        }
        for (int q = t; q < nq; q += T) {
            int i = lo + (q << 2);
            int4 e = *(const int4*)(idx + i);
            V27_H(e.x) V27_H(e.y) V27_H(e.z) V27_H(e.w)
        }
        for (int i = lo + (nq << 2) + t; i < hi; i += T) V27_H(idx[i]);
#undef V27_H
    }
    __syncthreads();
    unsigned short* row = cnt + (size_t)b * n + rbase;
    if ((((size_t)b * n + rbase) & 1) == 0) {
        unsigned* row32 = (unsigned*)row;
        int full = W >> 1;
        for (int i = t; i < full; i += T) row32[i] = (unsigned)lh[i];
        if ((W & 1) && t == 0)
            row[W - 1] = (unsigned short)(lh[W >> 1] & 0xffff);
    } else {
        for (int i = t; i < W; i += T)
            row[i] = (unsigned short)((lh[i >> 1] >> ((i & 1) << 4)) & 0xffff);
    }
}

// ---------------------------------------------------------------------------
// Fused: nsrc from cnt_out column sums; cnt_in column-wise exclusive prefix
// (in place, ushort: max in-degree << 65536) -> deg_in + ndst.
// ---------------------------------------------------------------------------
__global__ void v27_norm(const unsigned short* __restrict__ cnt_out,
                         unsigned short* __restrict__ cnt_in,
                         int* __restrict__ deg_in,
                         float* __restrict__ nsrc, float* __restrict__ ndst,
                         int n_src, int n_dst) {
    int i = blockIdx.x * blockDim.x + threadIdx.x;
    if (i < n_src) {
        const unsigned short* p = cnt_out + i;
        int s = 0;
        for (int b = 0; b < NB_OUT; ++b) { s += *p; p += n_src; }
        nsrc[i] = rsqrtf(fmaxf((float)s, 1.0f));
    }
    if (i < n_dst) {
        unsigned short* p = cnt_in + i;
        int a = 0;
        for (int b = 0; b < NB_IN; ++b) {
            int c = *p;
            *p = (unsigned short)a;
            a += c;
            p += n_dst;
        }
        deg_in[i] = a;
        ndst[i] = rsqrtf(fmaxf((float)a, 1.0f));
    }
}

// ---------------------------------------------------------------------------
// scan1 (proven): per-chunk totals of deg_in -> bsum.
// ---------------------------------------------------------------------------
__global__ void v23_scan1(const int* __restrict__ deg_in, int* __restrict__ bsum,
                          int n_dst, int chunk) {
    __shared__ int red[256];
    int b = blockIdx.x, t = threadIdx.x;
    int lo = b * chunk;
    int hi = lo + chunk; if (hi > n_dst) hi = n_dst;
    int s = 0;
    for (int i = lo + t; i < hi; i += 256) s += deg_in[i];
    red[t] = s;
    __syncthreads();
    for (int o = 128; o > 0; o >>= 1) {
        if (t < o) red[t] += red[t + o];
        __syncthreads();
    }
    if (t == 0) bsum[b] = red[0];
}

// ---------------------------------------------------------------------------
// scan23: every block redundantly HS-scans bsum[128] in LDS (parallel,
// uniform barriers), takes its own exclusive offset, then emits row_start
// for its chunk (proven scan3 body).
// ---------------------------------------------------------------------------
__global__ __launch_bounds__(256) void v31_scan23(
        const int* __restrict__ deg_in, const int* __restrict__ bsum,
        int* __restrict__ row_start, int n_dst, int chunk) {
    __shared__ int bs[SCAN_BLOCKS];
    __shared__ int tsum[256];
    int b = blockIdx.x, t = threadIdx.x;
    if (t < SCAN_BLOCKS) bs[t] = bsum[t];
    __syncthreads();
    for (int off = 1; off < SCAN_BLOCKS; off <<= 1) {
        int v = 0;
        if (t < SCAN_BLOCKS && t >= off) v = bs[t - off];
        __syncthreads();
        if (t < SCAN_BLOCKS) bs[t] += v;
        __syncthreads();
    }
    int lo = b * chunk;
    int hi = lo + chunk; if (hi > n_dst) hi = n_dst;
    int per = (chunk + 255) / 256;
    int mylo = lo + t * per;
    int myhi = mylo + per; if (myhi > hi) myhi = hi;
    int s = 0;
    for (int i = mylo; i < myhi; ++i) s += deg_in[i];
    tsum[t] = s;
    __syncthreads();
    if (t == 0) {
        int a = 0;
        for (int k = 0; k < 256; ++k) { int v = tsum[k]; tsum[k] = a; a += v; }
    }
    __syncthreads();
    int boffs = b ? bs[b - 1] : 0;
    int a = boffs + tsum[t];
    for (int i = mylo; i < myhi; ++i) { row_start[i] = a; a += deg_in[i]; }
    if (b == 0 && t == 0) row_start[n_dst] = bs[SCAN_BLOCKS - 1];
}

// ---------------------------------------------------------------------------
// Place (v31): LDS counter initialized FROM the block's prow slice (packed
// u16 pairs == the prow memory layout, coalesced u32 copy). atomicAdd then
// returns pre+rank combined: slot = row_start[d] + old16. No random global
// prow reads. pre+rank <= deg_in(d) (~<=60) << 65536: no cross-field carry.
// ---------------------------------------------------------------------------
__global__ __launch_bounds__(1024) void v31_place(
        const int* __restrict__ esrc, const int* __restrict__ edst,
        const unsigned short* __restrict__ pre, const int* __restrict__ row_start,
        int* __restrict__ sorted_src, int E, int n_dst, int Ec) {
    __shared__ unsigned int lh[PWORDS];
    int b = blockIdx.x, t = threadIdx.x, T = blockDim.x;
    int rbase = blockIdx.y * PRANGE;
    int rend = rbase + PRANGE; if (rend > n_dst) rend = n_dst;
    int W = rend - rbase;
    if (W <= 0) return;
    int Wp = (W + 1) >> 1;
    // prow slice base: (b*n_dst + rbase) u16s; both even -> 4B-aligned.
    const unsigned short* prow = pre + (size_t)b * n_dst + rbase;
    const unsigned int* prow32 = (const unsigned int*)prow;
    int full = W >> 1;
    for (int i = t; i < full; i += T) lh[i] = prow32[i];
    if ((W & 1) && t == 0) lh[Wp - 1] = (unsigned int)prow[W - 1];
    __syncthreads();
    int lo = b * Ec;
    int hi = lo + Ec; if (hi > E) hi = E;
    if (lo >= hi) return;
    int cntE = hi - lo;
    int nq = cntE >> 2;
#define V31_PL(dd, ss)                                                        \
    {                                                                         \
        unsigned r = (unsigned)((dd) - rbase);                                \
        if (r < (unsigned)W) {                                                \
            int sh = (r & 1) << 4;                                            \
            unsigned old = atomicAdd(&lh[r >> 1], 1u << sh);                  \
            int pr = (int)((old >> sh) & 0xffff);                             \
            int slot = row_start[dd] + pr;                                    \
            if ((unsigned)slot < (unsigned)E) sorted_src[slot] = (ss);        \
        }                                                                     \
    }
    for (int q = t; q < nq; q += T) {
        int i = lo + (q << 2);
        int4 dv = *(const int4*)(edst + i);
        int4 sv = *(const int4*)(esrc + i);
        V31_PL(dv.x, sv.x)
        V31_PL(dv.y, sv.y)
        V31_PL(dv.z, sv.z)
        V31_PL(dv.w, sv.w)
    }
    for (int i = lo + (nq << 2) + t; i < hi; i += T) {
        int d = edst[i];
        int s = esrc[i];
        V31_PL(d, s)
    }
#undef V31_PL
}

// ---------------------------------------------------------------------------
// Gather (proven v26 shape): wave = 1 dst row; 64 lanes = 4 edge-groups x
// 16 feature-lanes x float4. One VMEM instr covers 4 edges; 4-deep unroll.
// ---------------------------------------------------------------------------
__global__ void v26_gather(const float* __restrict__ feat,
                           const int* __restrict__ sorted_src,
                           const int* __restrict__ row_start,
                           const float* __restrict__ nsrc,
                           const float* __restrict__ ndst,
                           float* __restrict__ out,
                           int n_src, int n_dst) {
    int gid = blockIdx.x * blockDim.x + threadIdx.x;
    int d = gid >> 6;
    if (d >= n_dst) return;
    int lane = threadIdx.x & 63;
    int g = lane >> 4;          // edge slot within a 4-edge step
    int lg = lane & 15;         // feature chunk (float4)
    int lo = row_start[d], hi = row_start[d + 1];
    int nmax = n_src - 1;
    float4 a0 = {0,0,0,0}, a1 = {0,0,0,0}, a2 = {0,0,0,0}, a3 = {0,0,0,0};
#define V26_G(kk, acc)                                                        \
    {                                                                         \
        int s_ = sorted_src[(kk) + g];                                        \
        s_ = min(max(s_, 0), nmax);                                           \
        float w_ = nsrc[s_];                                                  \
        float4 v_ = *(const float4*)(feat + (size_t)s_ * NFEAT + (lg << 2));  \
        acc.x += v_.x * w_; acc.y += v_.y * w_;                               \
        acc.z += v_.z * w_; acc.w += v_.w * w_;                               \
    }
    int k = lo;
    for (; k + 15 < hi; k += 16) {
        V26_G(k, a0)
        V26_G(k + 4, a1)
        V26_G(k + 8, a2)
        V26_G(k + 12, a3)
    }
    for (; k + 3 < hi; k += 4) {
        V26_G(k, a0)
    }
    if (k + g < hi) {
        V26_G(k, a1)
    }
#undef V26_G
    float4 a;
    a.x = (a0.x + a1.x) + (a2.x + a3.x);
    a.y = (a0.y + a1.y) + (a2.y + a3.y);
    a.z = (a0.z + a1.z) + (a2.z + a3.z);
    a.w = (a0.w + a1.w) + (a2.w + a3.w);
    a.x += __shfl_xor(a.x, 16); a.x += __shfl_xor(a.x, 32);
    a.y += __shfl_xor(a.y, 16); a.y += __shfl_xor(a.y, 32);
    a.z += __shfl_xor(a.z, 16); a.z += __shfl_xor(a.z, 32);
    a.w += __shfl_xor(a.w, 16); a.w += __shfl_xor(a.w, 32);
    if (g == 0) {
        float sc = ndst[d];
        float4 r;
        r.x = a.x * sc; r.y = a.y * sc; r.z = a.z * sc; r.w = a.w * sc;
        *(float4*)(out + (size_t)d * NFEAT + (lg << 2)) = r;
    }
}

// ---------------------------------------------------------------------------
// v23 fallback (proven path) — only if ws_size can't hold the histograms
// ---------------------------------------------------------------------------

__global__ void v23_zero(int* __restrict__ deg_out, int* __restrict__ deg_in,
                         int n_src, int n_dst) {
    int i = blockIdx.x * blockDim.x + threadIdx.x;
    if (i < n_src) deg_out[i] = 0;
    if (i < n_dst) deg_in[i] = 0;
}

__global__ void v23_deg(const int* __restrict__ esrc, const int* __restrict__ edst,
                        int* __restrict__ deg_out, int* __restrict__ deg_in,
                        int E, int n_src, int n_dst) {
    int i = blockIdx.x * blockDim.x + threadIdx.x;
    if (i >= E) return;
    int s = esrc[i];
    int d = edst[i];
    if ((unsigned)s < (unsigned)n_src) atomicAdd(&deg_out[s], 1);
    if ((unsigned)d < (unsigned)n_dst) atomicAdd(&deg_in[d], 1);
}

__global__ void v23_norm(const int* __restrict__ deg_out, const int* __restrict__ deg_in,
                         float* __restrict__ nsrc, float* __restrict__ ndst,
                         int n_src, int n_dst) {
    int i = blockIdx.x * blockDim.x + threadIdx.x;
    if (i < n_src) nsrc[i] = rsqrtf(fmaxf((float)deg_out[i], 1.0f));
    if (i < n_dst) ndst[i] = rsqrtf(fmaxf((float)deg_in[i], 1.0f));
}

__global__ void v23_scan2(int* __restrict__ bsum, int* __restrict__ boff,
                          int* __restrict__ row_start, int n_dst) {
    if (threadIdx.x == 0) {
        int a = 0;
        for (int k = 0; k < SCAN_BLOCKS; ++k) { boff[k] = a; a += bsum[k]; }
        row_start[n_dst] = a;
    }
}

__global__ void v23_scan3(const int* __restrict__ deg_in, const int* __restrict__ boff,
                          int* __restrict__ row_start, int* __restrict__ cursor,
                          int n_dst, int chunk) {
    __shared__ int tsum[256];
    int b = blockIdx.x, t = threadIdx.x;
    int lo = b * chunk;
    int hi = lo + chunk; if (hi > n_dst) hi = n_dst;
    int per = (chunk + 255) / 256;
    int mylo = lo + t * per;
    int myhi = mylo + per; if (myhi > hi) myhi = hi;
    int s = 0;
    for (int i = mylo; i < myhi; ++i) s += deg_in[i];
    tsum[t] = s;
    __syncthreads();
    if (t == 0) {
        int a = 0;
        for (int k = 0; k < 256; ++k) { int v = tsum[k]; tsum[k] = a; a += v; }
    }
    __syncthreads();
    int a = boff[b] + tsum[t];
    for (int i = mylo; i < myhi; ++i) {
        row_start[i] = a;
        cursor[i] = a;
        a += deg_in[i];
    }
}

__global__ void v23_place(const int* __restrict__ esrc, const int* __restrict__ edst,
                          int* __restrict__ cursor, int* __restrict__ sorted_src,
                          int E, int n_src, int n_dst) {
    int i = blockIdx.x * blockDim.x + threadIdx.x;
    if (i >= E) return;
    int s = esrc[i];
    int d = edst[i];
    if ((unsigned)s >= (unsigned)n_src) return;
    if ((unsigned)d >= (unsigned)n_dst) return;
    int slot = atomicAdd(&cursor[d], 1);
    sorted_src[slot] = s;
}

// ---------------------------------------------------------------------------

extern "C" void kernel_launch(void* const* d_in, const int* in_sizes, int n_in,
                              void* d_out, int out_size, void* d_ws, size_t ws_size,
                              hipStream_t stream) {
    const float* feat = (const float*)d_in[0];
    const int* esrc = (const int*)d_in[1];
    const int* edst = (const int*)d_in[2];
    float* out = (float*)d_out;

    const int n_src = in_sizes[0] / NFEAT;   // 100000
    const int E     = in_sizes[1];           // 1250000
    const int n_dst = out_size / NFEAT;      // 50000

    const int B = 256;
    int nmax = n_src > n_dst ? n_src : n_dst;
    int chunk = (n_dst + SCAN_BLOCKS - 1) / SCAN_BLOCKS;

    size_t sz_cnt_in  = ((size_t)NB_IN  * (size_t)n_dst * 2 + 255) & ~(size_t)255;
    size_t sz_cnt_out = ((size_t)NB_OUT * (size_t)n_src * 2 + 255) & ~(size_t)255;
    size_t sz_fixed = (size_t)E * 4                 // sorted_src
                    + (size_t)n_dst * 4             // deg_in
                    + (size_t)n_src * 4             // nsrc
                    + (size_t)n_dst * 4             // ndst
                    + (size_t)n_dst * 4             // cursor
                    + (size_t)(n_dst + 1) * 4       // row_start
                    + (size_t)SCAN_BLOCKS * 8 + 512;
    bool big = ws_size >= sz_cnt_in + sz_cnt_out + sz_fixed;

    if (big) {
        char* ws = (char*)d_ws;
        size_t off = 0;
        unsigned short* cnt_in  = (unsigned short*)(ws + off); off += sz_cnt_in;
        unsigned short* cnt_out = (unsigned short*)(ws + off); off += sz_cnt_out;
        int*   sorted_src = (int*)(ws + off);   off += (size_t)E * 4;
        int*   deg_in     = (int*)(ws + off);   off += (size_t)n_dst * 4;
        float* nsrc       = (float*)(ws + off); off += (size_t)n_src * 4;
        float* ndst       = (float*)(ws + off); off += (size_t)n_dst * 4;
        int*   cursor     = (int*)(ws + off);   off += (size_t)n_dst * 4;
        int*   row_start  = (int*)(ws + off);   off += (size_t)(n_dst + 1) * 4;
        int*   bsum       = (int*)(ws + off);   off += SCAN_BLOCKS * 4;
        int*   boff       = (int*)(ws + off);   off += SCAN_BLOCKS * 4;
        (void)cursor; (void)boff;

        int Ec_in  = (((E + NB_IN  - 1) / NB_IN ) + 3) & ~3;   // 16B-aligned chunks
        int Ec_out = (((E + NB_OUT - 1) / NB_OUT) + 3) & ~3;
        int P_in  = (n_dst + PRANGE - 1) / PRANGE;             // 2
        int P_out = (n_src + PRANGE - 1) / PRANGE;             // 4

        dim3 gout(NB_OUT, P_out), gin(NB_IN, P_in);

        v27_hist<<<gout, 1024, 0, stream>>>(esrc, cnt_out, E, n_src, Ec_out);
        v27_hist<<<gin,  1024, 0, stream>>>(edst, cnt_in,  E, n_dst, Ec_in);
        v27_norm<<<(nmax + B - 1) / B, B, 0, stream>>>(cnt_out, cnt_in, deg_in,
                                                       nsrc, ndst, n_src, n_dst);
        v23_scan1<<<SCAN_BLOCKS, B, 0, stream>>>(deg_in, bsum, n_dst, chunk);
        v31_scan23<<<SCAN_BLOCKS, B, 0, stream>>>(deg_in, bsum, row_start,
                                                  n_dst, chunk);
        v31_place<<<gin, 1024, 0, stream>>>(esrc, edst, cnt_in, row_start,
                                            sorted_src, E, n_dst, Ec_in);
        long long gthreads = (long long)n_dst * 64;
        v26_gather<<<(int)((gthreads + B - 1) / B), B, 0, stream>>>(feat, sorted_src,
                                                                    row_start, nsrc, ndst,
                                                                    out, n_src, n_dst);
    } else {
        // v23 fallback layout
        char* ws = (char*)d_ws;
        size_t off = 0;
        int*   deg_out    = (int*)(ws + off);   off += (size_t)n_src * 4;
        int*   deg_in     = (int*)(ws + off);   off += (size_t)n_dst * 4;
        float* nsrc       = (float*)(ws + off); off += (size_t)n_src * 4;
        float* ndst       = (float*)(ws + off); off += (size_t)n_dst * 4;
        int*   row_start  = (int*)(ws + off);   off += (size_t)(n_dst + 1) * 4;
        int*   cursor     = (int*)(ws + off);   off += (size_t)n_dst * 4;
        int*   bsum       = (int*)(ws + off);   off += SCAN_BLOCKS * 4;
        int*   boff       = (int*)(ws + off);   off += SCAN_BLOCKS * 4;
        int*   sorted_src = (int*)(ws + off);   off += (size_t)E * 4;

        v23_zero<<<(nmax + B - 1) / B, B, 0, stream>>>(deg_out, deg_in, n_src, n_dst);
        v23_deg<<<(E + B - 1) / B, B, 0, stream>>>(esrc, edst, deg_out, deg_in,
                                                   E, n_src, n_dst);
        v23_norm<<<(nmax + B - 1) / B, B, 0, stream>>>(deg_out, deg_in, nsrc, ndst,
                                                       n_src, n_dst);
        v23_scan1<<<SCAN_BLOCKS, B, 0, stream>>>(deg_in, bsum, n_dst, chunk);
        v23_scan2<<<1, 64, 0, stream>>>(bsum, boff, row_start, n_dst);
        v23_scan3<<<SCAN_BLOCKS, B, 0, stream>>>(deg_in, boff, row_start, cursor,
                                                 n_dst, chunk);
        v23_place<<<(E + B - 1) / B, B, 0, stream>>>(esrc, edst, cursor, sorted_src,
                                                     E, n_src, n_dst);
        long long gthreads = (long long)n_dst * 64;
        v26_gather<<<(int)((gthreads + B - 1) / B), B, 0, stream>>>(feat, sorted_src,
                                                                    row_start, nsrc, ndst,
                                                                    out, n_src, n_dst);
    }
}